// Round 3
// baseline (202.739 us; speedup 1.0000x reference)
//
#include <hip/hip_runtime.h>
#include <hip/hip_bf16.h>

typedef __bf16 bf16_t;
typedef bf16_t bf16x8 __attribute__((ext_vector_type(8)));
typedef float f32x4 __attribute__((ext_vector_type(4)));

#define NODE_DIM 512
#define COND_DIM 512

// workspace layout (bytes)
#define WS_GA   0x000000   // gamma: 16x128 f32 = 8 KB
#define WS_BE   0x002000   // beta:  16x128 f32 = 8 KB
#define WS_P    0x010000   // P: 4096x256 bf16 = 2 MB

__device__ __forceinline__ bf16x8 cvt8(float4 a, float4 b) {
    bf16x8 v;
    v[0] = (bf16_t)a.x; v[1] = (bf16_t)a.y; v[2] = (bf16_t)a.z; v[3] = (bf16_t)a.w;
    v[4] = (bf16_t)b.x; v[5] = (bf16_t)b.y; v[6] = (bf16_t)b.z; v[7] = (bf16_t)b.w;
    return v;
}

// ---------------------------------------------------------------------------
// Kernel 1 (fused prep+gemm): 1280 blocks.
// blocks [0,256): 16-row M-tiles, 4 waves. All operands load fp32 DIRECTLY
//   from global and convert to bf16 in-register (no staging kernel, no
//   K-loop barriers). Weight-norm scale for v_node is computed inline: each
//   lane already loads its B-row's full K-slice, so sum(v^2) rides along the
//   MFMA loop and two shfl_xor(16/32) across the k-quarters finish the norm.
//   Phase 1: nodes16x128 = relu((A @ wn^T)*scale + b_node) -> LDS bf16.
//   Phase 2: P16x256 = nodes @ Wc^T with the concat-permutation folded into
//   wave-uniform w_film base pointers (n<128 <=> wave<2). Epilogue
//   transposes C-layout via LDS, 16-B coalesced bf16 stores to P.
// blocks [256,1280): gamma/beta = cond_feats @ weight_norm(v_cond)^T +
//   b_cond, one wave per output scalar. These 4096 waves co-reside with the
//   gemm tiles and hide the gemm K-loop's global-load latency.
// ---------------------------------------------------------------------------
__global__ __launch_bounds__(256) void fused_kernel(
    const float* __restrict__ node_feats, const float* __restrict__ cond_feats,
    const float* __restrict__ v_node, const float* __restrict__ g_node,
    const float* __restrict__ b_node, const float* __restrict__ v_cond,
    const float* __restrict__ g_cond, const float* __restrict__ b_cond,
    const float* __restrict__ w_film, char* __restrict__ ws)
{
    float* gamma = (float*)(ws + WS_GA);
    float* beta  = (float*)(ws + WS_BE);
    bf16_t* P = (bf16_t*)(ws + WS_P);

    int t = threadIdx.x;
    int lane = t & 63, w = t >> 6;

    if (blockIdx.x >= 256) {
        // ---- gamma/beta path ----
        int id = ((int)blockIdx.x - 256) * 4 + w;   // 0..4095
        int b = id >> 8, n = id & 255;
        const float* cf = cond_feats + b * COND_DIM + lane * 8;
        const float* vc = v_cond + (size_t)n * COND_DIM + lane * 8;
        float dot = 0.f, sq = 0.f;
#pragma unroll
        for (int i = 0; i < 2; i++) {
            float4 c4 = ((const float4*)cf)[i];
            float4 v4 = ((const float4*)vc)[i];
            dot += c4.x * v4.x + c4.y * v4.y + c4.z * v4.z + c4.w * v4.w;
            sq  += v4.x * v4.x + v4.y * v4.y + v4.z * v4.z + v4.w * v4.w;
        }
#pragma unroll
        for (int o = 32; o > 0; o >>= 1) {
            dot += __shfl_xor(dot, o);
            sq  += __shfl_xor(sq, o);
        }
        if (lane == 0) {
            float val = dot * (g_cond[n] * rsqrtf(sq)) + b_cond[n];
            if (n < 128) gamma[b * 128 + n] = val + 1.0f;
            else         beta[b * 128 + (n - 128)] = val;
        }
        return;
    }

    // ---- gemm path ----
    __shared__ __attribute__((aligned(16))) bf16_t N_s[16 * 136];
    __shared__ __attribute__((aligned(16))) float  T_s[4][16][68];

    int r16 = lane & 15, half = lane >> 4;
    int m0 = blockIdx.x * 16;

    f32x4 zero4 = {0.f, 0.f, 0.f, 0.f};

    // phase 1: wave w covers output cols [w*32, w*32+32)
    f32x4 acc0 = zero4, acc1 = zero4;
    float sq0 = 0.f, sq1 = 0.f;
    {
        const float* aptr = node_feats + (size_t)(m0 + r16) * NODE_DIM + half * 8;
        const float* b0p  = v_node + (size_t)(w * 32 + r16) * NODE_DIM + half * 8;
        const float* b1p  = b0p + 16 * NODE_DIM;
#pragma unroll
        for (int ks = 0; ks < 16; ks++) {
            float4 a0 = ((const float4*)(aptr + ks * 32))[0];
            float4 a1 = ((const float4*)(aptr + ks * 32))[1];
            float4 c0 = ((const float4*)(b0p + ks * 32))[0];
            float4 c1 = ((const float4*)(b0p + ks * 32))[1];
            float4 d0 = ((const float4*)(b1p + ks * 32))[0];
            float4 d1 = ((const float4*)(b1p + ks * 32))[1];
            sq0 += c0.x*c0.x + c0.y*c0.y + c0.z*c0.z + c0.w*c0.w
                 + c1.x*c1.x + c1.y*c1.y + c1.z*c1.z + c1.w*c1.w;
            sq1 += d0.x*d0.x + d0.y*d0.y + d0.z*d0.z + d0.w*d0.w
                 + d1.x*d1.x + d1.y*d1.y + d1.z*d1.z + d1.w*d1.w;
            bf16x8 af = cvt8(a0, a1);
            acc0 = __builtin_amdgcn_mfma_f32_16x16x32_bf16(af, cvt8(c0, c1), acc0, 0, 0, 0);
            acc1 = __builtin_amdgcn_mfma_f32_16x16x32_bf16(af, cvt8(d0, d1), acc1, 0, 0, 0);
        }
    }
    // finish row norms: lanes l, l^16, l^32, l^48 hold the 4 k-quarters
    sq0 += __shfl_xor(sq0, 16); sq0 += __shfl_xor(sq0, 32);
    sq1 += __shfl_xor(sq1, 16); sq1 += __shfl_xor(sq1, 32);

    // epilogue 1: C/D layout col=lane&15, row=(lane>>4)*4+reg -> N_s[row][col]
    {
        int rbase = half * 4;
#pragma unroll
        for (int j = 0; j < 2; j++) {
            int col = w * 32 + j * 16 + r16;
            float s = g_node[col] * rsqrtf(j ? sq1 : sq0);
            float bb = b_node[col];
            f32x4 a = j ? acc1 : acc0;
#pragma unroll
            for (int r = 0; r < 4; r++) {
                float v = fmaxf(a[r] * s + bb, 0.f);
                N_s[(rbase + r) * 136 + col] = (bf16_t)v;
            }
        }
    }
    __syncthreads();

    // phase 2: wave w covers output cols [w*64, w*64+64)
    f32x4 acc2[4];
#pragma unroll
    for (int i = 0; i < 4; i++) acc2[i] = zero4;
    {
        // concat permutation folded into base pointers; n<128 <=> w<2 (uniform)
        const float* wsrc[4];
#pragma unroll
        for (int j = 0; j < 4; j++) {
            int n = w * 64 + j * 16 + r16;
            wsrc[j] = (n < 128) ? (w_film + (size_t)n * 256 + half * 8)
                                : (w_film + (size_t)(n - 128) * 256 + 128 + half * 8);
        }
#pragma unroll
        for (int ks = 0; ks < 4; ks++) {
            bf16x8 af = *(const bf16x8*)&N_s[r16 * 136 + ks * 32 + half * 8];
#pragma unroll
            for (int j = 0; j < 4; j++) {
                float4 e0 = ((const float4*)(wsrc[j] + ks * 32))[0];
                float4 e1 = ((const float4*)(wsrc[j] + ks * 32))[1];
                acc2[j] = __builtin_amdgcn_mfma_f32_16x16x32_bf16(af, cvt8(e0, e1), acc2[j], 0, 0, 0);
            }
        }
    }
    // epilogue 2: transpose via LDS, then 16-B coalesced bf16 stores to P
    {
        int rbase = half * 4;
#pragma unroll
        for (int j = 0; j < 4; j++) {
            int col = j * 16 + r16;
#pragma unroll
            for (int r = 0; r < 4; r++) T_s[w][rbase + r][col] = acc2[j][r];
        }
    }
    __syncthreads();
    {
#pragma unroll
        for (int r2 = 0; r2 < 2; r2++) {
            int row = r2 * 8 + (lane >> 3);
            int colg = (lane & 7) * 8;
            float4 a = *(const float4*)&T_s[w][row][colg];
            float4 b = *(const float4*)&T_s[w][row][colg + 4];
            *(bf16x8*)&P[(size_t)(m0 + row) * 256 + w * 64 + colg] = cvt8(a, b);
        }
    }
}

// ---------------------------------------------------------------------------
// Kernel 2: per-edge gather + add + LayerNorm + FiLM + relu.
// 16 lanes per edge row, 8 cols per lane (bf16x8 gathers, 2x f32x4 NT
// stores). 8192 blocks, 32 consecutive rows per block, XCD-contiguous
// swizzle. A block's rows never cross a 16384-row batch boundary, so
// gamma/beta/b_film are hoisted.
// e = b*65536 + i*256 + j  =>  row_i = e>>8 ; row_j = (e>>16)<<8 | (e&255)
// ---------------------------------------------------------------------------
__global__ __launch_bounds__(256) void edge_kernel(
    const int* __restrict__ edges, const char* __restrict__ ws,
    const float* __restrict__ b_film, float* __restrict__ out)
{
    const bf16_t* P = (const bf16_t*)(ws + WS_P);
    const float* gamma = (const float*)(ws + WS_GA);
    const float* beta  = (const float*)(ws + WS_BE);

    int t = threadIdx.x;
    int l16  = t & 15;            // lane within row-group
    int rsub = t >> 4;            // 0..15: row within the 16-row iter tile
    int c = l16 * 8;              // col base, 8 cols per lane

    int base = (blockIdx.x & 7) * 32768 + (blockIdx.x >> 3) * 32;
    int bb = base >> 14;          // reshape batch, block-uniform

    float4 g0  = *(const float4*)&gamma[bb * 128 + c];
    float4 g1  = *(const float4*)&gamma[bb * 128 + c + 4];
    float4 be0 = *(const float4*)&beta[bb * 128 + c];
    float4 be1 = *(const float4*)&beta[bb * 128 + c + 4];
    float4 bf0 = *(const float4*)&b_film[c];
    float4 bf1 = *(const float4*)&b_film[c + 4];

#pragma unroll
    for (int it = 0; it < 2; it++) {
        int r = base + it * 16 + rsub;
        int e = edges[r];
        int ri = e >> 8;
        int rj = ((e >> 16) << 8) | (e & 255);

        bf16x8 p1 = *(const bf16x8*)&P[(size_t)ri * 256 + c];
        bf16x8 p2 = *(const bf16x8*)&P[(size_t)rj * 256 + 128 + c];

        float x0 = (float)p1[0] + (float)p2[0] + bf0.x;
        float x1 = (float)p1[1] + (float)p2[1] + bf0.y;
        float x2 = (float)p1[2] + (float)p2[2] + bf0.z;
        float x3 = (float)p1[3] + (float)p2[3] + bf0.w;
        float x4 = (float)p1[4] + (float)p2[4] + bf1.x;
        float x5 = (float)p1[5] + (float)p2[5] + bf1.y;
        float x6 = (float)p1[6] + (float)p2[6] + bf1.z;
        float x7 = (float)p1[7] + (float)p2[7] + bf1.w;

        float s  = ((x0 + x1) + (x2 + x3)) + ((x4 + x5) + (x6 + x7));
        float ss = x0 * x0 + x1 * x1 + x2 * x2 + x3 * x3
                 + x4 * x4 + x5 * x5 + x6 * x6 + x7 * x7;
#pragma unroll
        for (int m = 8; m >= 1; m >>= 1) {   // reduce across the 16-lane group
            s  += __shfl_xor(s, m);
            ss += __shfl_xor(ss, m);
        }
        float mu  = s * (1.0f / 128.0f);
        float var = ss * (1.0f / 128.0f) - mu * mu;
        float rs  = rsqrtf(var + 1e-5f);

        f32x4 o0, o1;
        o0[0] = fmaxf((x0 - mu) * rs * g0.x + be0.x, 0.f);
        o0[1] = fmaxf((x1 - mu) * rs * g0.y + be0.y, 0.f);
        o0[2] = fmaxf((x2 - mu) * rs * g0.z + be0.z, 0.f);
        o0[3] = fmaxf((x3 - mu) * rs * g0.w + be0.w, 0.f);
        o1[0] = fmaxf((x4 - mu) * rs * g1.x + be1.x, 0.f);
        o1[1] = fmaxf((x5 - mu) * rs * g1.y + be1.y, 0.f);
        o1[2] = fmaxf((x6 - mu) * rs * g1.z + be1.z, 0.f);
        o1[3] = fmaxf((x7 - mu) * rs * g1.w + be1.w, 0.f);

        __builtin_nontemporal_store(o0, (f32x4*)&out[(size_t)r * 128 + c]);
        __builtin_nontemporal_store(o1, (f32x4*)&out[(size_t)r * 128 + c + 4]);
    }
}

extern "C" void kernel_launch(void* const* d_in, const int* in_sizes, int n_in,
                              void* d_out, int out_size, void* d_ws, size_t ws_size,
                              hipStream_t stream) {
    const float* node_feats = (const float*)d_in[0];
    const float* cond_feats = (const float*)d_in[1];
    const int*   edges      = (const int*)d_in[2];
    const float* v_node     = (const float*)d_in[3];
    const float* g_node     = (const float*)d_in[4];
    const float* b_node     = (const float*)d_in[5];
    const float* v_cond     = (const float*)d_in[6];
    const float* g_cond     = (const float*)d_in[7];
    const float* b_cond     = (const float*)d_in[8];
    const float* w_film     = (const float*)d_in[9];
    const float* b_film     = (const float*)d_in[10];
    float* out = (float*)d_out;
    char* ws = (char*)d_ws;

    fused_kernel<<<1280, 256, 0, stream>>>(node_feats, cond_feats, v_node, g_node,
                                           b_node, v_cond, g_cond, b_cond, w_film, ws);
    edge_kernel<<<8192, 256, 0, stream>>>(edges, ws, b_film, out);
}

// Round 4
// 189.818 us; speedup vs baseline: 1.0681x; 1.0681x over previous
//
#include <hip/hip_runtime.h>
#include <hip/hip_bf16.h>

typedef __bf16 bf16_t;
typedef bf16_t bf16x8 __attribute__((ext_vector_type(8)));
typedef float f32x4 __attribute__((ext_vector_type(4)));

#define NODE_DIM 512
#define COND_DIM 512

// workspace layout (bytes)
#define WS_WN   0x000000   // v_node bf16: 128x512 = 128 KB
#define WS_WC   0x020000   // w_film bf16 (B^T perm): 256x128 = 64 KB
#define WS_SC   0x030000   // scale_node: 128 f32
#define WS_GA   0x031000   // gamma: 16x128 f32
#define WS_BE   0x033000   // beta: 16x128 f32
#define WS_P    0x040000   // P: 4096x256 bf16 = 2 MB

__device__ __forceinline__ bf16x8 cvt8(float4 a, float4 b) {
    bf16x8 v;
    v[0] = (bf16_t)a.x; v[1] = (bf16_t)a.y; v[2] = (bf16_t)a.z; v[3] = (bf16_t)a.w;
    v[4] = (bf16_t)b.x; v[5] = (bf16_t)b.y; v[6] = (bf16_t)b.z; v[7] = (bf16_t)b.w;
    return v;
}

// ---------------------------------------------------------------------------
// Kernel 1 (prep, 80 blocks — weight staging only, ~3 us serial):
// blocks [0,32):  v_node -> Wn bf16
// blocks [32,48): w_film -> Wc bf16 permuted (row n<128 = w_film[n][0:128],
//                 row n>=128 = w_film[n-128][128:256])
// blocks [48,80): scale_node[e] = g_node[e]/||v_node[e]|| (wave per row)
// gamma/beta moved into the gemm launch (no dependency on this kernel).
// ---------------------------------------------------------------------------
__global__ __launch_bounds__(256) void prep_kernel(
    const float* __restrict__ v_node, const float* __restrict__ g_node,
    const float* __restrict__ w_film, char* __restrict__ ws)
{
    bf16_t* Wn = (bf16_t*)(ws + WS_WN);
    bf16_t* Wc = (bf16_t*)(ws + WS_WC);
    float* scale_node = (float*)(ws + WS_SC);

    int t = threadIdx.x;
    int bid = blockIdx.x;
    int lane = t & 63, wv = t >> 6;

    if (bid < 32) {
        size_t idx = ((size_t)bid * 256 + t) * 8;
        float4 a = ((const float4*)(v_node + idx))[0];
        float4 b = ((const float4*)(v_node + idx))[1];
        *(bf16x8*)(Wn + idx) = cvt8(a, b);
    } else if (bid < 48) {
        int u = (bid - 32) * 256 + t;        // 0..4095, 8 elems each
        int n = u >> 4;                      // 0..255
        int ko = (u & 15) * 8;               // 0..120
        const float* src = (n < 128) ? (w_film + (size_t)n * 256 + ko)
                                     : (w_film + (size_t)(n - 128) * 256 + 128 + ko);
        float4 a = ((const float4*)src)[0];
        float4 b = ((const float4*)src)[1];
        *(bf16x8*)(Wc + (size_t)n * 128 + ko) = cvt8(a, b);
    } else {
        int id = (bid - 48) * 4 + wv;        // 0..127
        const float* vn = v_node + (size_t)id * NODE_DIM + lane * 8;
        float sq = 0.f;
#pragma unroll
        for (int i = 0; i < 2; i++) {
            float4 v4 = ((const float4*)vn)[i];
            sq += v4.x * v4.x + v4.y * v4.y + v4.z * v4.z + v4.w * v4.w;
        }
#pragma unroll
        for (int o = 32; o > 0; o >>= 1) sq += __shfl_xor(sq, o);
        if (lane == 0) scale_node[id] = g_node[id] * rsqrtf(sq);
    }
}

// ---------------------------------------------------------------------------
// Kernel 2 (gemm + gamma/beta, 1280 blocks):
// blocks [0,256): 16-row M-tiles, 4 waves. A-fragments load fp32 node_feats
//   DIRECTLY from global and convert in-register (lane l holds
//   X[row=l&15][k=(l>>4)*8+j]); B-operands are pre-staged bf16 (1 cvt8/iter).
//   Phase 1: nodes16x128 = relu((A16x512 @ Wn^T)*scale + b_node) -> LDS bf16.
//   Phase 2: P16x256 = nodes @ Wc^T; epilogue transposes via LDS, 16-B
//   coalesced bf16 stores to P.
// blocks [256,1280): gamma/beta = cond_feats @ weight_norm(v_cond)^T +
//   b_cond, one wave per output scalar. These 4096 waves co-reside with the
//   gemm tiles (~5 blocks/CU) and hide the gemm K-loop's global-load latency.
// ---------------------------------------------------------------------------
__global__ __launch_bounds__(256) void gemm_kernel(
    const float* __restrict__ node_feats, const float* __restrict__ cond_feats,
    const float* __restrict__ b_node, const float* __restrict__ v_cond,
    const float* __restrict__ g_cond, const float* __restrict__ b_cond,
    char* __restrict__ ws)
{
    float* gamma = (float*)(ws + WS_GA);
    float* beta  = (float*)(ws + WS_BE);
    bf16_t* P = (bf16_t*)(ws + WS_P);

    int t = threadIdx.x;
    int lane = t & 63, w = t >> 6;

    if (blockIdx.x >= 256) {
        // ---- gamma/beta path ----
        int id = ((int)blockIdx.x - 256) * 4 + w;   // 0..4095
        int b = id >> 8, n = id & 255;
        const float* cf = cond_feats + b * COND_DIM + lane * 8;
        const float* vc = v_cond + (size_t)n * COND_DIM + lane * 8;
        float dot = 0.f, sq = 0.f;
#pragma unroll
        for (int i = 0; i < 2; i++) {
            float4 c4 = ((const float4*)cf)[i];
            float4 v4 = ((const float4*)vc)[i];
            dot += c4.x * v4.x + c4.y * v4.y + c4.z * v4.z + c4.w * v4.w;
            sq  += v4.x * v4.x + v4.y * v4.y + v4.z * v4.z + v4.w * v4.w;
        }
#pragma unroll
        for (int o = 32; o > 0; o >>= 1) {
            dot += __shfl_xor(dot, o);
            sq  += __shfl_xor(sq, o);
        }
        if (lane == 0) {
            float val = dot * (g_cond[n] * rsqrtf(sq)) + b_cond[n];
            if (n < 128) gamma[b * 128 + n] = val + 1.0f;
            else         beta[b * 128 + (n - 128)] = val;
        }
        return;
    }

    // ---- gemm path ----
    const bf16_t* Wn = (const bf16_t*)(ws + WS_WN);
    const bf16_t* Wc = (const bf16_t*)(ws + WS_WC);
    const float* scale_node = (const float*)(ws + WS_SC);

    __shared__ __attribute__((aligned(16))) bf16_t N_s[16 * 136];
    __shared__ __attribute__((aligned(16))) float  T_s[4][16][68];

    int r16 = lane & 15, half = lane >> 4;
    int m0 = blockIdx.x * 16;

    f32x4 zero4 = {0.f, 0.f, 0.f, 0.f};

    // phase 1: wave w covers output cols [w*32, w*32+32)
    f32x4 acc0 = zero4, acc1 = zero4;
    {
        const float*  aptr = node_feats + (size_t)(m0 + r16) * NODE_DIM + half * 8;
        const bf16_t* bptr = Wn + (size_t)(w * 32 + r16) * NODE_DIM + half * 8;
#pragma unroll
        for (int ks = 0; ks < 16; ks++) {
            float4 a0 = ((const float4*)(aptr + ks * 32))[0];
            float4 a1 = ((const float4*)(aptr + ks * 32))[1];
            bf16x8 af = cvt8(a0, a1);
            bf16x8 b0 = *(const bf16x8*)(bptr + ks * 32);
            bf16x8 b1 = *(const bf16x8*)(bptr + 16 * NODE_DIM + ks * 32);
            acc0 = __builtin_amdgcn_mfma_f32_16x16x32_bf16(af, b0, acc0, 0, 0, 0);
            acc1 = __builtin_amdgcn_mfma_f32_16x16x32_bf16(af, b1, acc1, 0, 0, 0);
        }
    }
    // epilogue 1: C/D layout col=lane&15, row=(lane>>4)*4+reg -> N_s[row][col]
    {
        int rbase = half * 4;
#pragma unroll
        for (int j = 0; j < 2; j++) {
            int col = w * 32 + j * 16 + r16;
            float s = scale_node[col], bb = b_node[col];
            f32x4 a = j ? acc1 : acc0;
#pragma unroll
            for (int r = 0; r < 4; r++) {
                float v = fmaxf(a[r] * s + bb, 0.f);
                N_s[(rbase + r) * 136 + col] = (bf16_t)v;
            }
        }
    }
    __syncthreads();

    // phase 2: wave w covers output cols [w*64, w*64+64)
    f32x4 acc2[4];
#pragma unroll
    for (int i = 0; i < 4; i++) acc2[i] = zero4;
    {
        const bf16_t* bptr = Wc + (size_t)(w * 64 + r16) * 128 + half * 8;
#pragma unroll
        for (int ks = 0; ks < 4; ks++) {
            bf16x8 af = *(const bf16x8*)&N_s[r16 * 136 + ks * 32 + half * 8];
#pragma unroll
            for (int j = 0; j < 4; j++) {
                bf16x8 bf = *(const bf16x8*)(bptr + j * 16 * 128 + ks * 32);
                acc2[j] = __builtin_amdgcn_mfma_f32_16x16x32_bf16(af, bf, acc2[j], 0, 0, 0);
            }
        }
    }
    // epilogue 2: transpose via LDS, then 16-B coalesced bf16 stores to P
    {
        int rbase = half * 4;
#pragma unroll
        for (int j = 0; j < 4; j++) {
            int col = j * 16 + r16;
#pragma unroll
            for (int r = 0; r < 4; r++) T_s[w][rbase + r][col] = acc2[j][r];
        }
    }
    __syncthreads();
    {
#pragma unroll
        for (int r2 = 0; r2 < 2; r2++) {
            int row = r2 * 8 + (lane >> 3);
            int colg = (lane & 7) * 8;
            float4 a = *(const float4*)&T_s[w][row][colg];
            float4 b = *(const float4*)&T_s[w][row][colg + 4];
            *(bf16x8*)&P[(size_t)(m0 + row) * 256 + w * 64 + colg] = cvt8(a, b);
        }
    }
}

// ---------------------------------------------------------------------------
// Kernel 3: per-edge gather + add + LayerNorm + FiLM + relu.
// 16 lanes per edge row, 8 cols per lane (bf16x8 gathers, 2x f32x4 NT
// stores). 8192 blocks, 32 consecutive rows per block, XCD-contiguous
// swizzle. A block's rows never cross a 16384-row batch boundary, so
// gamma/beta/b_film are hoisted.
// e = b*65536 + i*256 + j  =>  row_i = e>>8 ; row_j = (e>>16)<<8 | (e&255)
// ---------------------------------------------------------------------------
__global__ __launch_bounds__(256) void edge_kernel(
    const int* __restrict__ edges, const char* __restrict__ ws,
    const float* __restrict__ b_film, float* __restrict__ out)
{
    const bf16_t* P = (const bf16_t*)(ws + WS_P);
    const float* gamma = (const float*)(ws + WS_GA);
    const float* beta  = (const float*)(ws + WS_BE);

    int t = threadIdx.x;
    int l16  = t & 15;            // lane within row-group
    int rsub = t >> 4;            // 0..15: row within the 16-row iter tile
    int c = l16 * 8;              // col base, 8 cols per lane

    int base = (blockIdx.x & 7) * 32768 + (blockIdx.x >> 3) * 32;
    int bb = base >> 14;          // reshape batch, block-uniform

    float4 g0  = *(const float4*)&gamma[bb * 128 + c];
    float4 g1  = *(const float4*)&gamma[bb * 128 + c + 4];
    float4 be0 = *(const float4*)&beta[bb * 128 + c];
    float4 be1 = *(const float4*)&beta[bb * 128 + c + 4];
    float4 bf0 = *(const float4*)&b_film[c];
    float4 bf1 = *(const float4*)&b_film[c + 4];

#pragma unroll
    for (int it = 0; it < 2; it++) {
        int r = base + it * 16 + rsub;
        int e = edges[r];
        int ri = e >> 8;
        int rj = ((e >> 16) << 8) | (e & 255);

        bf16x8 p1 = *(const bf16x8*)&P[(size_t)ri * 256 + c];
        bf16x8 p2 = *(const bf16x8*)&P[(size_t)rj * 256 + 128 + c];

        float x0 = (float)p1[0] + (float)p2[0] + bf0.x;
        float x1 = (float)p1[1] + (float)p2[1] + bf0.y;
        float x2 = (float)p1[2] + (float)p2[2] + bf0.z;
        float x3 = (float)p1[3] + (float)p2[3] + bf0.w;
        float x4 = (float)p1[4] + (float)p2[4] + bf1.x;
        float x5 = (float)p1[5] + (float)p2[5] + bf1.y;
        float x6 = (float)p1[6] + (float)p2[6] + bf1.z;
        float x7 = (float)p1[7] + (float)p2[7] + bf1.w;

        float s  = ((x0 + x1) + (x2 + x3)) + ((x4 + x5) + (x6 + x7));
        float ss = x0 * x0 + x1 * x1 + x2 * x2 + x3 * x3
                 + x4 * x4 + x5 * x5 + x6 * x6 + x7 * x7;
#pragma unroll
        for (int m = 8; m >= 1; m >>= 1) {   // reduce across the 16-lane group
            s  += __shfl_xor(s, m);
            ss += __shfl_xor(ss, m);
        }
        float mu  = s * (1.0f / 128.0f);
        float var = ss * (1.0f / 128.0f) - mu * mu;
        float rs  = rsqrtf(var + 1e-5f);

        f32x4 o0, o1;
        o0[0] = fmaxf((x0 - mu) * rs * g0.x + be0.x, 0.f);
        o0[1] = fmaxf((x1 - mu) * rs * g0.y + be0.y, 0.f);
        o0[2] = fmaxf((x2 - mu) * rs * g0.z + be0.z, 0.f);
        o0[3] = fmaxf((x3 - mu) * rs * g0.w + be0.w, 0.f);
        o1[0] = fmaxf((x4 - mu) * rs * g1.x + be1.x, 0.f);
        o1[1] = fmaxf((x5 - mu) * rs * g1.y + be1.y, 0.f);
        o1[2] = fmaxf((x6 - mu) * rs * g1.z + be1.z, 0.f);
        o1[3] = fmaxf((x7 - mu) * rs * g1.w + be1.w, 0.f);

        __builtin_nontemporal_store(o0, (f32x4*)&out[(size_t)r * 128 + c]);
        __builtin_nontemporal_store(o1, (f32x4*)&out[(size_t)r * 128 + c + 4]);
    }
}

extern "C" void kernel_launch(void* const* d_in, const int* in_sizes, int n_in,
                              void* d_out, int out_size, void* d_ws, size_t ws_size,
                              hipStream_t stream) {
    const float* node_feats = (const float*)d_in[0];
    const float* cond_feats = (const float*)d_in[1];
    const int*   edges      = (const int*)d_in[2];
    const float* v_node     = (const float*)d_in[3];
    const float* g_node     = (const float*)d_in[4];
    const float* b_node     = (const float*)d_in[5];
    const float* v_cond     = (const float*)d_in[6];
    const float* g_cond     = (const float*)d_in[7];
    const float* b_cond     = (const float*)d_in[8];
    const float* w_film     = (const float*)d_in[9];
    const float* b_film     = (const float*)d_in[10];
    float* out = (float*)d_out;
    char* ws = (char*)d_ws;

    prep_kernel<<<80, 256, 0, stream>>>(v_node, g_node, w_film, ws);
    gemm_kernel<<<1280, 256, 0, stream>>>(node_feats, cond_feats, b_node,
                                          v_cond, g_cond, b_cond, ws);
    edge_kernel<<<8192, 256, 0, stream>>>(edges, ws, b_film, out);
}